// Round 1
// baseline (2167.757 us; speedup 1.0000x reference)
//
#include <hip/hip_runtime.h>

// SHGR kNN head: cosine distance, top-16, inverse-distance weighted target average.
// B=2048, N=100000, D=128, T=8, k=16 (k hardcoded; setup always passes 16).
//
// Pipeline:
//   1. norm_rows_k: L2-normalize supports & queries -> bf16 (ushort bits) in ws.
//   2. score_select_k: bf16 MFMA similarity + per-(slice,half) approx top-16.
//   3. merge_refine_k: merge 512 cands/query -> approx top-32 -> exact (f64) refine
//      -> exact top-16 -> weights -> gather targets -> out.

#define NSLICES 32
#define CN 64      // supports per chunk
#define BQ 128     // queries per block
#define SCP 68     // padded score row stride (floats); 68*4B = 272B (16B-aligned, bank-spread)

typedef __bf16 bf16x8 __attribute__((ext_vector_type(8)));
typedef float f32x4 __attribute__((ext_vector_type(4)));

__device__ __forceinline__ ushort f2bf(float f) {
  unsigned u = __float_as_uint(f);
  unsigned r = (u + 0x7FFFu + ((u >> 16) & 1u)) >> 16;  // RNE
  return (ushort)r;
}

// Normalize rows of x [nrows][128] -> bf16 bits. One wave per row.
__global__ __launch_bounds__(256) void norm_rows_k(const float* __restrict__ x,
                                                   ushort* __restrict__ xb,
                                                   int nrows) {
  int row = blockIdx.x * 4 + (threadIdx.x >> 6);
  int lane = threadIdx.x & 63;
  if (row >= nrows) return;
  float2 v = *reinterpret_cast<const float2*>(x + (size_t)row * 128 + lane * 2);
  float ss = v.x * v.x + v.y * v.y;
  #pragma unroll
  for (int o = 1; o < 64; o <<= 1) ss += __shfl_xor(ss, o);
  float inv = 1.0f / fmaxf(sqrtf(ss), 1e-12f);
  ushort2 h = make_ushort2(f2bf(v.x * inv), f2bf(v.y * inv));
  *reinterpret_cast<ushort2*>(xb + (size_t)row * 128 + lane * 2) = h;
}

// Approx scoring + per-slice selection.
// Grid: (B/BQ, NSLICES). 256 threads = 4 waves; wave w owns queries w*32..w*32+31
// (2 MFMA row-subtiles); all waves share a 64-support LDS chunk (4 col-tiles each).
__global__ __launch_bounds__(256) void score_select_k(
    const ushort* __restrict__ qn, const ushort* __restrict__ sn,
    float2* __restrict__ cand, int N) {
  __shared__ ushort st[64 * 128];     // support chunk, 16B-block XOR-swizzled per row
  __shared__ float sc[BQ * SCP];      // score transpose buffer
  const int tid = threadIdx.x;
  const int w = tid >> 6;
  const int lane = tid & 63;
  const int g = lane >> 4;
  const int m = lane & 15;
  const int qbase = blockIdx.x * BQ;
  const int slice = blockIdx.y;
  const int SLICE = (N + NSLICES - 1) / NSLICES;
  const int slice_start = slice * SLICE;
  const int slice_end = min(N, slice_start + SLICE);

  // A-fragments (queries) in registers: feature map k = 32*t + 8*g + e, row = m.
  // Same (lane,elem)->k map is used for B, so any HW k-permutation cancels.
  bf16x8 afr[2][4];
  #pragma unroll
  for (int sub = 0; sub < 2; ++sub) {
    int qrow = qbase + w * 32 + sub * 16 + m;
    #pragma unroll
    for (int t = 0; t < 4; ++t)
      afr[sub][t] = *reinterpret_cast<const bf16x8*>(qn + (size_t)qrow * 128 + t * 32 + g * 8);
  }

  // Per-thread top-16 (sorted descending). Registers only (static indexing).
  float ls[16];
  int li[16];
  #pragma unroll
  for (int i = 0; i < 16; ++i) { ls[i] = -3.0e38f; li[i] = -1; }

  const int qs = tid & (BQ - 1);  // query this thread scans
  const int h = tid >> 7;         // which 32-column half

  const int nchunks = (slice_end - slice_start + CN - 1) / CN;
  for (int ch = 0; ch < nchunks; ++ch) {
    const int cbase = slice_start + ch * CN;
    __syncthreads();  // prev chunk's st reads & sc reads done
    // Stage 64x128 bf16 (16KB): linear global -> XOR-swizzled LDS (breaks the
    // stride-256B b128 bank conflict on the B-fragment reads).
    #pragma unroll
    for (int r = 0; r < 4; ++r) {
      int o = r * 4096 + tid * 16;     // linear byte offset in tile
      int row = o >> 8;                // 0..63
      int j = (o >> 4) & 15;           // 16B block in row
      int srow = min(cbase + row, slice_end - 1);  // clamp tail
      uint4 v = *reinterpret_cast<const uint4*>(sn + (size_t)srow * 128 + j * 8);
      int dj = j ^ (row & 7);
      *reinterpret_cast<uint4*>(&st[row * 128 + dj * 8]) = v;
    }
    __syncthreads();
    // MFMA: 2 q-subtiles x 4 col-tiles x K=128
    #pragma unroll
    for (int ct = 0; ct < 4; ++ct) {
      const int srow = ct * 16 + m;
      f32x4 acc0 = {0.f, 0.f, 0.f, 0.f}, acc1 = {0.f, 0.f, 0.f, 0.f};
      #pragma unroll
      for (int t = 0; t < 4; ++t) {
        int cj = (4 * t + g) ^ (srow & 7);
        bf16x8 bfr = *reinterpret_cast<const bf16x8*>(&st[srow * 128 + cj * 8]);
        acc0 = __builtin_amdgcn_mfma_f32_16x16x32_bf16(afr[0][t], bfr, acc0, 0, 0, 0);
        acc1 = __builtin_amdgcn_mfma_f32_16x16x32_bf16(afr[1][t], bfr, acc1, 0, 0, 0);
      }
      // C/D layout (m89/m91): col = lane&15, row = (lane>>4)*4 + reg
      const int col = ct * 16 + m;
      #pragma unroll
      for (int e = 0; e < 4; ++e) {
        sc[(w * 32 + g * 4 + e) * SCP + col] = acc0[e];
        sc[(w * 32 + 16 + g * 4 + e) * SCP + col] = acc1[e];
      }
    }
    __syncthreads();
    // Scan: 2 threads per query, 32 cols each; rare bubble-insert into top-16.
    const int colbase = h * 32;
    #pragma unroll
    for (int j4 = 0; j4 < 8; ++j4) {
      float4 v = *reinterpret_cast<const float4*>(&sc[qs * SCP + colbase + j4 * 4]);
      float vv[4] = {v.x, v.y, v.z, v.w};
      #pragma unroll
      for (int e = 0; e < 4; ++e) {
        float s = vv[e];
        if (s > ls[15]) {
          int sid = cbase + colbase + j4 * 4 + e;
          if (sid < slice_end) {
            float cs = s; int ci = sid;
            #pragma unroll
            for (int i = 0; i < 16; ++i) {
              bool sw = cs > ls[i];
              float tf = ls[i]; int ti = li[i];
              if (sw) { ls[i] = cs; li[i] = ci; cs = tf; ci = ti; }
            }
          }
        }
      }
    }
  }
  // Merge the two halves of each query; h==0 writes slice-local top-16.
  __syncthreads();
  float2* cl = reinterpret_cast<float2*>(sc);
  if (h == 1) {
    #pragma unroll
    for (int i = 0; i < 16; ++i) cl[qs * 16 + i] = make_float2(ls[i], __int_as_float(li[i]));
  }
  __syncthreads();
  if (h == 0) {
    #pragma unroll
    for (int i = 0; i < 16; ++i) {
      float2 e2 = cl[qs * 16 + i];
      if (e2.x > ls[15]) {
        float cs = e2.x; int ci = __float_as_int(e2.y);
        #pragma unroll
        for (int ii = 0; ii < 16; ++ii) {
          bool sw = cs > ls[ii];
          float tf = ls[ii]; int ti = li[ii];
          if (sw) { ls[ii] = cs; li[ii] = ci; cs = tf; ci = ti; }
        }
      }
    }
    float2* dst = cand + ((size_t)(qbase + qs) * NSLICES + slice) * 16;
    #pragma unroll
    for (int i = 0; i < 16; ++i) dst[i] = make_float2(ls[i], __int_as_float(li[i]));
  }
}

// One wave per query: merge 512 candidates -> approx top-32 -> exact refine
// (f32 normalize semantics, f64 accumulation) -> exact top-16 -> weighted output.
__global__ __launch_bounds__(64) void merge_refine_k(
    const float* __restrict__ query, const float* __restrict__ supports,
    const float* __restrict__ targets, const float2* __restrict__ cand,
    float* __restrict__ out) {
  const int q = blockIdx.x;
  const int lane = threadIdx.x;
  float2 c[8];
  #pragma unroll
  for (int i = 0; i < 8; ++i) c[i] = cand[(size_t)q * (NSLICES * 16) + lane * 8 + i];

  // Approx top-32 by repeated wave-argmax (carry (val, slot); owner invalidates).
  int rs = -1;  // lane it<32 holds selected support idx
  for (int it = 0; it < 32; ++it) {
    float bv = -3.0e38f;
    int bslot = lane * 8;
    #pragma unroll
    for (int i = 0; i < 8; ++i)
      if (c[i].x > bv) { bv = c[i].x; bslot = lane * 8 + i; }
    #pragma unroll
    for (int o = 1; o < 64; o <<= 1) {
      float ov = __shfl_xor(bv, o);
      int os = __shfl_xor(bslot, o);
      if (ov > bv || (ov == bv && os < bslot)) { bv = ov; bslot = os; }
    }
    int widx = 0;
    if ((bslot >> 3) == lane) {
      #pragma unroll
      for (int i = 0; i < 8; ++i)
        if (i == (bslot & 7)) { widx = __float_as_int(c[i].y); c[i].x = -3.0e38f; }
    }
    widx = __shfl(widx, bslot >> 3);
    if (lane == it) rs = widx;
  }

  // q-hat: f32 division by f32 norm (sum in f64 -> below numpy's own noise).
  float2 qv = *reinterpret_cast<const float2*>(query + (size_t)q * 128 + lane * 2);
  double qss = (double)qv.x * qv.x + (double)qv.y * qv.y;
  #pragma unroll
  for (int o = 1; o < 64; o <<= 1) qss += __shfl_xor(qss, o);
  float qn1 = fmaxf((float)sqrt(qss), 1e-12f);
  float qhx = qv.x / qn1, qhy = qv.y / qn1;

  float dv = 3.0e38f;  // refined distance at lanes 0..31
  for (int cc = 0; cc < 32; ++cc) {
    int sidx = __shfl(rs, cc);
    float2 sv = *reinterpret_cast<const float2*>(supports + (size_t)sidx * 128 + lane * 2);
    double sss = (double)sv.x * sv.x + (double)sv.y * sv.y;
    #pragma unroll
    for (int o = 1; o < 64; o <<= 1) sss += __shfl_xor(sss, o);
    float sn1 = fmaxf((float)sqrt(sss), 1e-12f);
    float shx = sv.x / sn1, shy = sv.y / sn1;
    double p = (double)qhx * shx + (double)qhy * shy;
    #pragma unroll
    for (int o = 1; o < 64; o <<= 1) p += __shfl_xor(p, o);
    float d = (float)(1.0 - p);
    if (lane == cc) dv = d;
  }

  // Exact top-16 (tie-break: lower support index, matching lax.top_k).
  float myd = 0.f; int myidx = -1;
  for (int it = 0; it < 16; ++it) {
    float bd = dv; int bi = rs;
    #pragma unroll
    for (int o = 1; o < 64; o <<= 1) {
      float od = __shfl_xor(bd, o);
      int oi = __shfl_xor(bi, o);
      if (od < bd || (od == bd && (unsigned)oi < (unsigned)bi)) { bd = od; bi = oi; }
    }
    if (lane == it) { myd = bd; myidx = bi; }
    if (rs == bi) dv = 3.0e38f;  // invalidate winner (indices unique)
  }

  // Weights + gather targets (lanes 0..15 hold selection).
  float wv = (lane < 16) ? 1.0f / (myd + 1e-8f) : 0.0f;
  float wsum = wv;
  #pragma unroll
  for (int o = 1; o < 64; o <<= 1) wsum += __shfl_xor(wsum, o);
  float acc[8];
  #pragma unroll
  for (int t = 0; t < 8; ++t) acc[t] = 0.f;
  if (lane < 16) {
    float wn = wv / wsum;
    const float* tp = targets + (size_t)myidx * 8;
    #pragma unroll
    for (int t = 0; t < 8; ++t) acc[t] = wn * tp[t];
  }
  #pragma unroll
  for (int o = 1; o < 64; o <<= 1) {
    #pragma unroll
    for (int t = 0; t < 8; ++t) acc[t] += __shfl_xor(acc[t], o);
  }
  if (lane == 0) {
    #pragma unroll
    for (int t = 0; t < 8; ++t) out[(size_t)q * 8 + t] = acc[t];
  }
}

extern "C" void kernel_launch(void* const* d_in, const int* in_sizes, int n_in,
                              void* d_out, int out_size, void* d_ws, size_t ws_size,
                              hipStream_t stream) {
  const float* query = (const float*)d_in[0];
  const float* supports = (const float*)d_in[1];
  const float* targets = (const float*)d_in[2];
  float* out = (float*)d_out;
  const int D = 128;
  const int B = in_sizes[0] / D;   // 2048
  const int N = in_sizes[1] / D;   // 100000

  char* ws = (char*)d_ws;
  size_t off = 0;
  ushort* sn = (ushort*)(ws + off); off += (size_t)N * D * 2;
  off = (off + 255) & ~(size_t)255;
  ushort* qn = (ushort*)(ws + off); off += (size_t)B * D * 2;
  off = (off + 255) & ~(size_t)255;
  float2* cand = (float2*)(ws + off); off += (size_t)B * NSLICES * 16 * sizeof(float2);
  if (off > ws_size) return;  // fail loudly (validation will catch) rather than corrupt

  hipLaunchKernelGGL(norm_rows_k, dim3((N + 3) / 4), dim3(256), 0, stream, supports, sn, N);
  hipLaunchKernelGGL(norm_rows_k, dim3((B + 3) / 4), dim3(256), 0, stream, query, qn, B);
  hipLaunchKernelGGL(score_select_k, dim3(B / BQ, NSLICES), dim3(256), 0, stream, qn, sn, cand, N);
  hipLaunchKernelGGL(merge_refine_k, dim3(B), dim3(64), 0, stream, query, supports, targets, cand, out);
}

// Round 2
// 427.703 us; speedup vs baseline: 5.0684x; 5.0684x over previous
//
#include <hip/hip_runtime.h>

// SHGR kNN head: cosine distance, top-16, inverse-distance weighted target average.
// B=2048, N=100000, D=128, T=8, k=16.
//
// Pipeline:
//   1. norm_rows_k: L2-normalize supports & queries -> bf16 (ushort bits) in ws.
//   2. score_select_k: two-pass threshold select.
//        pass 1: bf16 MFMA, per-(query,chunk) max from accumulator registers.
//        thr[q] = 16th largest chunk-max (bitonic-64)  [provably <= true 16th score]
//        pass 2: recompute scores (bitwise identical), append scores >= thr to
//                a small LDS candidate buffer (~19 expected, CAP=48), final
//                bitonic-64 -> slice top-16.
//   3. merge_refine_k: merge 512 cands/query -> approx top-32 -> exact (f64) refine
//      -> exact top-16 -> weights -> gather targets -> out.

#define NSLICES 32
#define CN 64      // supports per chunk
#define BQ 128     // queries per block
#define CAP 48     // candidate buffer capacity per query (expected ~19 hits)
#define CMP 52     // cm row stride (ushorts)

typedef __bf16 bf16x8 __attribute__((ext_vector_type(8)));
typedef float f32x4 __attribute__((ext_vector_type(4)));

__device__ __forceinline__ ushort f2bf(float f) {
  unsigned u = __float_as_uint(f);
  unsigned r = (u + 0x7FFFu + ((u >> 16) & 1u)) >> 16;  // RNE
  return (ushort)r;
}

// Full-wave bitonic sort, ascending in (v, i). Lane 63 ends with the largest.
__device__ __forceinline__ void bitonic64(float& v, unsigned& i, int lane) {
  #pragma unroll
  for (int k = 2; k <= 64; k <<= 1) {
    #pragma unroll
    for (int j = k >> 1; j > 0; j >>= 1) {
      float pv = __shfl_xor(v, j);
      unsigned pi = (unsigned)__shfl_xor((int)i, j);
      bool up = ((lane & k) == 0);
      bool lower = ((lane & j) == 0);
      bool gt = (v > pv) || (v == pv && i > pi);
      bool keep = (up == lower) ? !gt : gt;
      if (!keep) { v = pv; i = pi; }
    }
  }
}

// Normalize rows of x [nrows][128] -> bf16 bits. One wave per row.
__global__ __launch_bounds__(256) void norm_rows_k(const float* __restrict__ x,
                                                   ushort* __restrict__ xb,
                                                   int nrows) {
  int row = blockIdx.x * 4 + (threadIdx.x >> 6);
  int lane = threadIdx.x & 63;
  if (row >= nrows) return;
  float2 v = *reinterpret_cast<const float2*>(x + (size_t)row * 128 + lane * 2);
  float ss = v.x * v.x + v.y * v.y;
  #pragma unroll
  for (int o = 1; o < 64; o <<= 1) ss += __shfl_xor(ss, o);
  float inv = 1.0f / fmaxf(sqrtf(ss), 1e-12f);
  ushort2 h = make_ushort2(f2bf(v.x * inv), f2bf(v.y * inv));
  *reinterpret_cast<ushort2*>(xb + (size_t)row * 128 + lane * 2) = h;
}

// Two-pass threshold top-16 per (query, slice).
// Grid: (B/BQ, NSLICES). 256 threads = 4 waves; wave w owns queries w*32..w*32+31.
__global__ __launch_bounds__(256) void score_select_k(
    const ushort* __restrict__ qn, const ushort* __restrict__ sn,
    float2* __restrict__ cand, int N) {
  __shared__ ushort st[64 * 128];     // 16KB support chunk, XOR-swizzled
  __shared__ ushort cm[BQ * CMP];     // 13.3KB chunk maxes (truncated bf16 bits)
  __shared__ float2 cbuf[BQ * CAP];   // 48KB candidate buffer
  __shared__ unsigned cnt[BQ];
  __shared__ float thr_l[BQ];

  const int tid = threadIdx.x;
  const int w = tid >> 6;
  const int lane = tid & 63;
  const int g = lane >> 4;
  const int m = lane & 15;
  const int qbase = blockIdx.x * BQ;
  const int slice = blockIdx.y;
  const int SLICE = (N + NSLICES - 1) / NSLICES;
  const int s0 = slice * SLICE;
  const int s1 = min(N, s0 + SLICE);
  const int nch = (s1 - s0 + CN - 1) / CN;  // <= 49 (< 64 required)

  if (tid < BQ) cnt[tid] = 0;

  // A-fragments (queries) in registers: k = 32*t + 8*g + e, row = m.
  // Same (lane,elem)->k map for B, so any HW k-permutation cancels.
  bf16x8 afr[2][4];
  #pragma unroll
  for (int sub = 0; sub < 2; ++sub) {
    int qrow = qbase + w * 32 + sub * 16 + m;
    #pragma unroll
    for (int t = 0; t < 4; ++t)
      afr[sub][t] = *reinterpret_cast<const bf16x8*>(qn + (size_t)qrow * 128 + t * 32 + g * 8);
  }

  // ---------------- pass 1: per-(query,chunk) maxes ----------------
  for (int ch = 0; ch < nch; ++ch) {
    const int cb = s0 + ch * CN;
    __syncthreads();
    #pragma unroll
    for (int r = 0; r < 4; ++r) {
      int o = r * 4096 + tid * 16;
      int row = o >> 8;
      int j = (o >> 4) & 15;
      int srow = min(cb + row, s1 - 1);
      uint4 v = *reinterpret_cast<const uint4*>(sn + (size_t)srow * 128 + j * 8);
      int dj = j ^ (row & 7);
      *reinterpret_cast<uint4*>(&st[row * 128 + dj * 8]) = v;
    }
    __syncthreads();
    float rmax[2][4];
    #pragma unroll
    for (int sub = 0; sub < 2; ++sub)
      #pragma unroll
      for (int e = 0; e < 4; ++e) rmax[sub][e] = -3.0e38f;
    #pragma unroll
    for (int ct = 0; ct < 4; ++ct) {
      const int srow = ct * 16 + m;
      f32x4 a0 = {0.f, 0.f, 0.f, 0.f}, a1 = {0.f, 0.f, 0.f, 0.f};
      #pragma unroll
      for (int t = 0; t < 4; ++t) {
        int cj = (4 * t + g) ^ (srow & 7);
        bf16x8 bfr = *reinterpret_cast<const bf16x8*>(&st[srow * 128 + cj * 8]);
        a0 = __builtin_amdgcn_mfma_f32_16x16x32_bf16(afr[0][t], bfr, a0, 0, 0, 0);
        a1 = __builtin_amdgcn_mfma_f32_16x16x32_bf16(afr[1][t], bfr, a1, 0, 0, 0);
      }
      #pragma unroll
      for (int e = 0; e < 4; ++e) {
        rmax[0][e] = fmaxf(rmax[0][e], a0[e]);
        rmax[1][e] = fmaxf(rmax[1][e], a1[e]);
      }
    }
    // reduce over the 16 m-lanes (columns); row = w*32 + sub*16 + g*4 + e
    #pragma unroll
    for (int sub = 0; sub < 2; ++sub)
      #pragma unroll
      for (int e = 0; e < 4; ++e) {
        float v = rmax[sub][e];
        #pragma unroll
        for (int o = 1; o < 16; o <<= 1) v = fmaxf(v, __shfl_xor(v, o));
        rmax[sub][e] = v;
      }
    if (m == 0) {
      #pragma unroll
      for (int sub = 0; sub < 2; ++sub)
        #pragma unroll
        for (int e = 0; e < 4; ++e) {
          int row = w * 32 + sub * 16 + g * 4 + e;
          // truncate (round toward smaller magnitude) -> stored max <= true max
          cm[row * CMP + ch] = (ushort)(__float_as_uint(rmax[sub][e]) >> 16);
        }
    }
  }

  // ---------------- threshold: 16th largest chunk-max ----------------
  // (wave-private data: cm rows written and read by the owning wave only)
  for (int qq = 0; qq < 32; ++qq) {
    int q = w * 32 + qq;
    float v = (lane < nch) ? __uint_as_float(((unsigned)cm[q * CMP + lane]) << 16) : -3.0e38f;
    unsigned ii = (unsigned)lane;
    bitonic64(v, ii, lane);
    float t = __shfl(v, 48);  // 16th largest
    if (lane == 0) thr_l[q] = t;
  }
  float thrv[2][4];
  #pragma unroll
  for (int sub = 0; sub < 2; ++sub)
    #pragma unroll
    for (int e = 0; e < 4; ++e)
      thrv[sub][e] = thr_l[w * 32 + sub * 16 + g * 4 + e];

  // ---------------- pass 2: filter & collect ----------------
  for (int ch = 0; ch < nch; ++ch) {
    const int cb = s0 + ch * CN;
    __syncthreads();
    #pragma unroll
    for (int r = 0; r < 4; ++r) {
      int o = r * 4096 + tid * 16;
      int row = o >> 8;
      int j = (o >> 4) & 15;
      int srow = min(cb + row, s1 - 1);
      uint4 v = *reinterpret_cast<const uint4*>(sn + (size_t)srow * 128 + j * 8);
      int dj = j ^ (row & 7);
      *reinterpret_cast<uint4*>(&st[row * 128 + dj * 8]) = v;
    }
    __syncthreads();
    const int vcols = min(CN, s1 - cb);
    #pragma unroll
    for (int ct = 0; ct < 4; ++ct) {
      const int srow = ct * 16 + m;
      f32x4 a0 = {0.f, 0.f, 0.f, 0.f}, a1 = {0.f, 0.f, 0.f, 0.f};
      #pragma unroll
      for (int t = 0; t < 4; ++t) {
        int cj = (4 * t + g) ^ (srow & 7);
        bf16x8 bfr = *reinterpret_cast<const bf16x8*>(&st[srow * 128 + cj * 8]);
        a0 = __builtin_amdgcn_mfma_f32_16x16x32_bf16(afr[0][t], bfr, a0, 0, 0, 0);
        a1 = __builtin_amdgcn_mfma_f32_16x16x32_bf16(afr[1][t], bfr, a1, 0, 0, 0);
      }
      const int col = ct * 16 + m;
      const bool cv = col < vcols;
      bool h0[4], h1[4];
      bool any = false;
      #pragma unroll
      for (int e = 0; e < 4; ++e) {
        h0[e] = cv && (a0[e] >= thrv[0][e]);
        h1[e] = cv && (a1[e] >= thrv[1][e]);
        any = any || h0[e] || h1[e];
      }
      if (__any(any)) {
        #pragma unroll
        for (int e = 0; e < 4; ++e) {
          if (h0[e]) {
            int q = w * 32 + g * 4 + e;
            unsigned p = atomicAdd(&cnt[q], 1u);
            if (p < CAP) cbuf[q * CAP + p] = make_float2(a0[e], __int_as_float(cb + col));
          }
          if (h1[e]) {
            int q = w * 32 + 16 + g * 4 + e;
            unsigned p = atomicAdd(&cnt[q], 1u);
            if (p < CAP) cbuf[q * CAP + p] = make_float2(a1[e], __int_as_float(cb + col));
          }
        }
      }
    }
  }

  // ---------------- final: top-16 of candidates ----------------
  for (int qq = 0; qq < 32; ++qq) {
    int q = w * 32 + qq;
    unsigned mc = min(cnt[q], (unsigned)CAP);
    float v = -3.0e38f;
    unsigned ii = 0u;  // safe idx for (should-never-happen) padding
    if ((unsigned)lane < mc) {
      float2 e2 = cbuf[q * CAP + lane];
      v = e2.x;
      ii = (unsigned)__float_as_int(e2.y);
    }
    bitonic64(v, ii, lane);
    if (lane >= 48) {
      float2* dst = cand + ((size_t)(qbase + q) * NSLICES + slice) * 16;
      dst[lane - 48] = make_float2(v, __int_as_float((int)ii));
    }
  }
}

// One wave per query: merge 512 candidates -> approx top-32 -> exact refine
// (f32 normalize semantics, f64 accumulation) -> exact top-16 -> weighted output.
__global__ __launch_bounds__(64) void merge_refine_k(
    const float* __restrict__ query, const float* __restrict__ supports,
    const float* __restrict__ targets, const float2* __restrict__ cand,
    float* __restrict__ out) {
  const int q = blockIdx.x;
  const int lane = threadIdx.x;
  float2 c[8];
  #pragma unroll
  for (int i = 0; i < 8; ++i) c[i] = cand[(size_t)q * (NSLICES * 16) + lane * 8 + i];

  // Approx top-32 by repeated wave-argmax (carry (val, slot); owner invalidates).
  int rs = -1;  // lane it<32 holds selected support idx
  for (int it = 0; it < 32; ++it) {
    float bv = -3.0e38f;
    int bslot = lane * 8;
    #pragma unroll
    for (int i = 0; i < 8; ++i)
      if (c[i].x > bv) { bv = c[i].x; bslot = lane * 8 + i; }
    #pragma unroll
    for (int o = 1; o < 64; o <<= 1) {
      float ov = __shfl_xor(bv, o);
      int os = __shfl_xor(bslot, o);
      if (ov > bv || (ov == bv && os < bslot)) { bv = ov; bslot = os; }
    }
    int widx = 0;
    if ((bslot >> 3) == lane) {
      #pragma unroll
      for (int i = 0; i < 8; ++i)
        if (i == (bslot & 7)) { widx = __float_as_int(c[i].y); c[i].x = -3.0e38f; }
    }
    widx = __shfl(widx, bslot >> 3);
    if (lane == it) rs = widx;
  }

  // q-hat: f32 division by f32 norm (sum in f64 -> below numpy's own noise).
  float2 qv = *reinterpret_cast<const float2*>(query + (size_t)q * 128 + lane * 2);
  double qss = (double)qv.x * qv.x + (double)qv.y * qv.y;
  #pragma unroll
  for (int o = 1; o < 64; o <<= 1) qss += __shfl_xor(qss, o);
  float qn1 = fmaxf((float)sqrt(qss), 1e-12f);
  float qhx = qv.x / qn1, qhy = qv.y / qn1;

  float dv = 3.0e38f;  // refined distance at lanes 0..31
  for (int cc = 0; cc < 32; ++cc) {
    int sidx = __shfl(rs, cc);
    float2 sv = *reinterpret_cast<const float2*>(supports + (size_t)sidx * 128 + lane * 2);
    double sss = (double)sv.x * sv.x + (double)sv.y * sv.y;
    #pragma unroll
    for (int o = 1; o < 64; o <<= 1) sss += __shfl_xor(sss, o);
    float sn1 = fmaxf((float)sqrt(sss), 1e-12f);
    float shx = sv.x / sn1, shy = sv.y / sn1;
    double p = (double)qhx * shx + (double)qhy * shy;
    #pragma unroll
    for (int o = 1; o < 64; o <<= 1) p += __shfl_xor(p, o);
    float d = (float)(1.0 - p);
    if (lane == cc) dv = d;
  }

  // Exact top-16 (tie-break: lower support index, matching lax.top_k).
  float myd = 0.f; int myidx = -1;
  for (int it = 0; it < 16; ++it) {
    float bd = dv; int bi = rs;
    #pragma unroll
    for (int o = 1; o < 64; o <<= 1) {
      float od = __shfl_xor(bd, o);
      int oi = __shfl_xor(bi, o);
      if (od < bd || (od == bd && (unsigned)oi < (unsigned)bi)) { bd = od; bi = oi; }
    }
    if (lane == it) { myd = bd; myidx = bi; }
    if (rs == bi) dv = 3.0e38f;  // invalidate winner (indices unique)
  }

  // Weights + gather targets (lanes 0..15 hold selection).
  float wv = (lane < 16) ? 1.0f / (myd + 1e-8f) : 0.0f;
  float wsum = wv;
  #pragma unroll
  for (int o = 1; o < 64; o <<= 1) wsum += __shfl_xor(wsum, o);
  float acc[8];
  #pragma unroll
  for (int t = 0; t < 8; ++t) acc[t] = 0.f;
  if (lane < 16) {
    float wn = wv / wsum;
    const float* tp = targets + (size_t)myidx * 8;
    #pragma unroll
    for (int t = 0; t < 8; ++t) acc[t] = wn * tp[t];
  }
  #pragma unroll
  for (int o = 1; o < 64; o <<= 1) {
    #pragma unroll
    for (int t = 0; t < 8; ++t) acc[t] += __shfl_xor(acc[t], o);
  }
  if (lane == 0) {
    #pragma unroll
    for (int t = 0; t < 8; ++t) out[(size_t)q * 8 + t] = acc[t];
  }
}

extern "C" void kernel_launch(void* const* d_in, const int* in_sizes, int n_in,
                              void* d_out, int out_size, void* d_ws, size_t ws_size,
                              hipStream_t stream) {
  const float* query = (const float*)d_in[0];
  const float* supports = (const float*)d_in[1];
  const float* targets = (const float*)d_in[2];
  float* out = (float*)d_out;
  const int D = 128;
  const int B = in_sizes[0] / D;   // 2048
  const int N = in_sizes[1] / D;   // 100000

  char* ws = (char*)d_ws;
  size_t off = 0;
  ushort* sn = (ushort*)(ws + off); off += (size_t)N * D * 2;
  off = (off + 255) & ~(size_t)255;
  ushort* qn = (ushort*)(ws + off); off += (size_t)B * D * 2;
  off = (off + 255) & ~(size_t)255;
  float2* cand = (float2*)(ws + off); off += (size_t)B * NSLICES * 16 * sizeof(float2);
  if (off > ws_size) return;

  hipLaunchKernelGGL(norm_rows_k, dim3((N + 3) / 4), dim3(256), 0, stream, supports, sn, N);
  hipLaunchKernelGGL(norm_rows_k, dim3((B + 3) / 4), dim3(256), 0, stream, query, qn, B);
  hipLaunchKernelGGL(score_select_k, dim3(B / BQ, NSLICES), dim3(256), 0, stream, qn, sn, cand, N);
  hipLaunchKernelGGL(merge_refine_k, dim3(B), dim3(64), 0, stream, query, supports, targets, cand, out);
}